// Round 13
// baseline (1662.856 us; speedup 1.0000x reference)
//
#include <hip/hip_runtime.h>

typedef unsigned short u16;
typedef unsigned int u32;
typedef _Float16 f16;
typedef _Float16 half8 __attribute__((ext_vector_type(8)));
typedef _Float16 half4 __attribute__((ext_vector_type(4)));
typedef float f32x4 __attribute__((ext_vector_type(4)));

#define SPLIT_SC 2048.0f
#define SPLIT_INV (1.0f / 2048.0f)

__device__ __forceinline__ float sigf(float x) { return 1.0f / (1.0f + expf(-x)); }

// ---------------------------------------------------------------------------
// Fused attention-params + filterbank + glimpse, v4 (round-10 verified).
// ---------------------------------------------------------------------------
__global__ __launch_bounds__(256) void att_glimpse(
    const f16* __restrict__ h_hi, const f16* __restrict__ h_lo,
    const float* __restrict__ Watt, const float* __restrict__ batt,
    const float* __restrict__ x,
    f16* __restrict__ r_hi, f16* __restrict__ r_lo)
{
    __shared__ float simg[64 * 64];      // 16 KB, this channel, [y][a]
    __shared__ float sFx[16 * 68];       // [xo][a], stride 68
    __shared__ float sFyT[64 * 20];      // [y][n],  stride 20
    __shared__ float stmp[16 * 68];      // [n][a],  stride 68
    __shared__ float sred[4 * 5];
    __shared__ float spar[8];

    const int b = blockIdx.x, c = blockIdx.y, tid = threadIdx.x;
    const int lane = tid & 63, wave = tid >> 6;

    {
        const float4* src = (const float4*)(x + (size_t)b * 12288 + c * 4096);
        float4* dst = (float4*)simg;
        for (int i = tid; i < 1024; i += 256) dst[i] = src[i];
    }

    float p[5] = {0.f, 0.f, 0.f, 0.f, 0.f};
    {
        const f16* hh = h_hi + (size_t)b * 1024;
        const f16* hl = h_lo + (size_t)b * 1024;
        for (int k = tid; k < 1024; k += 256) {
            float hv = (float)hh[k] + (float)hl[k] * SPLIT_INV;
#pragma unroll
            for (int j = 0; j < 5; j++) p[j] += hv * Watt[j * 1024 + k];
        }
#pragma unroll
        for (int j = 0; j < 5; j++) {
#pragma unroll
            for (int o = 32; o > 0; o >>= 1) p[j] += __shfl_xor(p[j], o);
        }
        if (lane == 0) {
#pragma unroll
            for (int j = 0; j < 5; j++) sred[wave * 5 + j] = p[j];
        }
    }
    __syncthreads();
    if (tid == 0) {
        float q[5];
#pragma unroll
        for (int j = 0; j < 5; j++)
            q[j] = sred[j] + sred[5 + j] + sred[10 + j] + sred[15 + j] + batt[j];
        float q2 = fminf(fmaxf(q[2], -60.f), 60.f);
        float q3 = fminf(fmaxf(q[3], -60.f), 60.f);
        float q4 = fminf(fmaxf(q[4], -60.f), 60.f);
        spar[0] = 32.5f * (q[0] + 1.0f);          // gx
        spar[1] = 32.5f * (q[1] + 1.0f);          // gy
        spar[2] = 0.5f * expf(-q2);               // 1/(2*sigma2)
        spar[3] = 4.2f * expf(q3);                // delta
        spar[4] = expf(q4);                       // gamma
    }
    __syncthreads();
    const float gx = spar[0], gy = spar[1], inv2s2 = spar[2], dl = spar[3],
                gamma = spar[4];

    {
        const float af = (float)lane;
#pragma unroll
        for (int i = 0; i < 4; i++) {
            int n = wave + i * 4;
            float nn = (float)n - 8.5f;
            float mux = gx + nn * dl;
            float ex = af - mux;
            float vx = expf(-ex * ex * inv2s2);
            float sx = vx;
#pragma unroll
            for (int o = 32; o > 0; o >>= 1) sx += __shfl_xor(sx, o);
            sFx[n * 68 + lane] = vx / (sx + 1e-8f);

            float muy = gy + nn * dl;
            float ey = af - muy;
            float vy = expf(-ey * ey * inv2s2);
            float sy = vy;
#pragma unroll
            for (int o = 32; o > 0; o >>= 1) sy += __shfl_xor(sy, o);
            sFyT[lane * 20 + n] = vy / (sy + 1e-8f);   // transposed [y][n]
        }
    }
    __syncthreads();

    // stage 1 (all 4 waves): tmp[n][a] = sum_y Fy[n][y] * img[y][a]
    {
        const int n4 = wave, ysub = lane >> 4, a4 = lane & 15;
        f32x4 acc[4];
#pragma unroll
        for (int j = 0; j < 4; j++) acc[j] = (f32x4)(0.f);
        for (int yy = 0; yy < 16; yy++) {
            int y = ysub * 16 + yy;
            float4 im = *(const float4*)(simg + y * 64 + a4 * 4);
            float4 fy = *(const float4*)(sFyT + y * 20 + n4 * 4);
            f32x4 iv = {im.x, im.y, im.z, im.w};
            acc[0] += fy.x * iv;
            acc[1] += fy.y * iv;
            acc[2] += fy.z * iv;
            acc[3] += fy.w * iv;
        }
#pragma unroll
        for (int j = 0; j < 4; j++) {
#pragma unroll
            for (int o = 16; o <= 32; o <<= 1) {
                acc[j].x += __shfl_xor(acc[j].x, o);
                acc[j].y += __shfl_xor(acc[j].y, o);
                acc[j].z += __shfl_xor(acc[j].z, o);
                acc[j].w += __shfl_xor(acc[j].w, o);
            }
        }
        if (ysub == 0) {
#pragma unroll
            for (int j = 0; j < 4; j++)
                *(f32x4*)(stmp + (n4 * 4 + j) * 68 + a4 * 4) = acc[j];
        }
    }
    __syncthreads();

    {
        const int n = tid >> 4, xo = tid & 15;
        const float* tp = stmp + n * 68;
        const float* fx = sFx + xo * 68;
        float s = 0.f;
        for (int a = 0; a < 64; a += 4) {
            float4 t4 = *(const float4*)(tp + a);
            float4 x4 = *(const float4*)(fx + a);
            s += t4.x * x4.x + t4.y * x4.y + t4.z * x4.z + t4.w * x4.w;
        }
        float v = s * gamma;
        f16 hi = (f16)v;
        size_t idx = (size_t)b * 768 + c * 256 + tid;
        r_hi[idx] = hi;
        r_lo[idx] = (f16)((v - (float)hi) * SPLIT_SC);
    }
}

// ---------------------------------------------------------------------------
// W pre-swizzle v2 (round-12 verified): gate = (c&1)*2 + (l15>>3),
// u_local = (c>>1)*8 + (l15&7) -> lane pairs (l15, l15^8) hold all 4 gates.
// ---------------------------------------------------------------------------
__global__ __launch_bounds__(256) void swz_w(
    const float* __restrict__ W1, const float* __restrict__ W2,
    f16* __restrict__ out)
{
    const int kc = blockIdx.x >> 5, bn = blockIdx.x & 31;
    for (int t = threadIdx.x; t < 512; t += 256) {
        int c = t >> 6, lane = t & 63, l15 = lane & 15, lq = lane >> 4;
        int gate = ((c & 1) << 1) + (l15 >> 3);
        int ul   = ((c >> 1) << 3) + (l15 & 7);
        int wrow = gate * 1024 + bn * 32 + ul;
        const float* src;
        if (kc < 24) src = W1 + (size_t)wrow * 768 + kc * 32 + lq * 8;
        else         src = W2 + (size_t)wrow * 1024 + (kc - 24) * 32 + lq * 8;
        float4 g0 = *(const float4*)src;
        float4 g1 = *(const float4*)(src + 4);
        float gv[8] = {g0.x, g0.y, g0.z, g0.w, g1.x, g1.y, g1.z, g1.w};
        half8 hv, lv;
#pragma unroll
        for (int j = 0; j < 8; j++) {
            f16 h = (f16)gv[j];
            hv[j] = h;
            lv[j] = (f16)((gv[j] - (float)h) * SPLIT_SC);
        }
        size_t base = ((size_t)(kc * 32 + bn) * 16 + c * 2) * 512 + (size_t)lane * 8;
        *(half8*)(out + base) = hv;
        *(half8*)(out + base + 512) = lv;
    }
}

// ---------------------------------------------------------------------------
// Fused gates GEMM + LSTM pointwise, v8.
// 32-row x 128-col blocks -> grid 1024 = 4 blocks/CU (was 512 = 2/CU; the
// grid was the occupancy limiter: 1blk=83us, 2blk=57us measured).
// Wave = 2 m-tiles x 2 c-tiles (disjoint B, v7-verified epilogue).
// A LDS dbuf 10.25 KB; same pipeline & bit-identical accumulation as v7.
// ---------------------------------------------------------------------------
#define LDH 40   // A LDS row stride in f16 elems (80 B)

__global__ __launch_bounds__(256, 4) void gates_lstm(
    const f16* __restrict__ A1h, const f16* __restrict__ A1l,  // r [1024][768]
    const f16* __restrict__ A2h, const f16* __restrict__ A2l,  // h [1024][1024]
    const f16* __restrict__ Wswz,                               // swizzled W
    const float* __restrict__ b1, const float* __restrict__ b2,
    float* __restrict__ cst,
    f16* __restrict__ Hh, f16* __restrict__ Hl)
{
    __shared__ f16 sA[2][2][32 * LDH];   // [buf][plane] 10.25 KB total
    const int tid = threadIdx.x;
    const int kb = blockIdx.x;           // 0..1023
    const int xcd = kb & 7, jb = kb >> 3;  // jb 0..127
    const int bn = xcd * 4 + (jb & 3);   // 0..31
    const int bm = jb >> 2;              // 0..31  (32-row tiles)
    const int wave = tid >> 6, lane = tid & 63;
    const int cbase = wave * 2;          // disjoint ctile pair per wave
    const int l15 = lane & 15, lq = lane >> 4;
    // A stage mapping: plane = tid>>7 (wave-uniform), row = (tid&127)>>2,
    // col = (tid&3)*8  -> 1 uint4 per thread covers 32x32x2 planes.
    const int aplane = tid >> 7, arow = (tid & 127) >> 2, acol = (tid & 3) * 8;

    f32x4 ah[2][2], al[2][2];
#pragma unroll
    for (int i = 0; i < 2; i++)
#pragma unroll
        for (int j = 0; j < 2; j++) { ah[i][j] = (f32x4)(0.f); al[i][j] = (f32x4)(0.f); }

    // prologue: stage A(kc=0) into buf0, load B(kc=0) fragments
    {
        const f16* pa = aplane ? A1l : A1h;
        size_t aoff = (size_t)(bm * 32 + arow) * 768 + acol;
        *(uint4*)&sA[0][aplane][arow * LDH + acol] = *(const uint4*)(pa + aoff);
    }
    half8 Bc[4];
    {
        const f16* wb = Wswz + (size_t)bn * 16 * 512 + (size_t)lane * 8;
#pragma unroll
        for (int nt = 0; nt < 2; nt++) {
            Bc[nt * 2]     = *(const half8*)(wb + (cbase + nt) * 1024);
            Bc[nt * 2 + 1] = *(const half8*)(wb + (cbase + nt) * 1024 + 512);
        }
    }

#pragma unroll 2
    for (int i = 0; i < 56; ++i) {
        const int cur = i & 1;
        __syncthreads();                 // buf[cur] ready, prev reads drained
        const int kn = (i + 1 < 56) ? i + 1 : 55;
        // ---- prefetch A(kn) to regs ----
        const f16 *pah, *pal; int astr, ako;
        if (kn < 24) { pah = A1h; pal = A1l; astr = 768;  ako = kn * 32; }
        else         { pah = A2h; pal = A2l; astr = 1024; ako = (kn - 24) * 32; }
        const f16* pa = aplane ? pal : pah;
        size_t aoff = (size_t)(bm * 32 + arow) * astr + ako + acol;
        uint4 va = *(const uint4*)(pa + aoff);
        // ---- prefetch B(kn) fragments ----
        half8 Bn[4];
        {
            const f16* wb = Wswz + (size_t)(kn * 32 + bn) * 16 * 512 + (size_t)lane * 8;
#pragma unroll
            for (int nt = 0; nt < 2; nt++) {
                Bn[nt * 2]     = *(const half8*)(wb + (cbase + nt) * 1024);
                Bn[nt * 2 + 1] = *(const half8*)(wb + (cbase + nt) * 1024 + 512);
            }
        }
        // ---- compute on buf[cur] with Bc: 2 m-tiles x 2 c-tiles ----
        half8 afh[2], afl[2];
#pragma unroll
        for (int mt = 0; mt < 2; mt++) {
            int ro = (mt * 16 + l15) * LDH + lq * 8;
            afh[mt] = *(const half8*)&sA[cur][0][ro];
            afl[mt] = *(const half8*)&sA[cur][1][ro];
        }
#pragma unroll
        for (int mt = 0; mt < 2; mt++)
#pragma unroll
            for (int nt = 0; nt < 2; nt++) {
                ah[mt][nt] = __builtin_amdgcn_mfma_f32_16x16x32_f16(
                    afh[mt], Bc[nt * 2], ah[mt][nt], 0, 0, 0);
                al[mt][nt] = __builtin_amdgcn_mfma_f32_16x16x32_f16(
                    afh[mt], Bc[nt * 2 + 1], al[mt][nt], 0, 0, 0);
                al[mt][nt] = __builtin_amdgcn_mfma_f32_16x16x32_f16(
                    afl[mt], Bc[nt * 2], al[mt][nt], 0, 0, 0);
            }
        // ---- write prefetched A into the other buffer, rotate B ----
        const int nxt = cur ^ 1;
        *(uint4*)&sA[nxt][aplane][arow * LDH + acol] = va;
#pragma unroll
        for (int q = 0; q < 4; q++) Bc[q] = Bn[q];
    }

    // epilogue: lane holds gates {g0, g0+2} (g0 = l15>>3) at
    // u = bn*32 + wave*8 + (l15&7); partner lane l15^8 holds the other pair.
    const int g0 = l15 >> 3;
    const int u = bn * 32 + wave * 8 + (l15 & 7);
    const float bv0 = b1[g0 * 1024 + u] + b2[g0 * 1024 + u];
    const float bv1 = b1[(g0 + 2) * 1024 + u] + b2[(g0 + 2) * 1024 + u];
#pragma unroll
    for (int mt = 0; mt < 2; mt++) {
#pragma unroll
        for (int rg = 0; rg < 4; rg++) {
            int row = bm * 32 + mt * 16 + lq * 4 + rg;
            size_t idx = (size_t)row * 1024 + u;
            float mine0 = ah[mt][0][rg] + al[mt][0][rg] * SPLIT_INV + bv0;
            float mine1 = ah[mt][1][rg] + al[mt][1][rg] * SPLIT_INV + bv1;
            float oth0 = __shfl_xor(mine0, 8);
            float oth1 = __shfl_xor(mine1, 8);
            float gi = (g0 == 0) ? mine0 : oth0;
            float gg = (g0 == 0) ? mine1 : oth1;
            float gf = (g0 == 0) ? oth0 : mine0;
            float go = (g0 == 0) ? oth1 : mine1;
            if (g0 == 0) {
                float cn = sigf(gf) * cst[idx] + sigf(gi) * tanhf(gg);
                float hn = sigf(go) * tanhf(cn);
                cst[idx] = cn;
                f16 hh = (f16)hn;
                Hh[idx] = hh;
                Hl[idx] = (f16)((hn - (float)hh) * SPLIT_SC);
            }
        }
    }
}

// ---------------------------------------------------------------------------
// fc0 v3 (round-10 verified): 64x64 tiles, grid (16,16).
// ---------------------------------------------------------------------------
__global__ __launch_bounds__(256) void fc0_gemm(
    const f16* __restrict__ Ah, const f16* __restrict__ Al,
    const float* __restrict__ W, const float* __restrict__ bias,
    float* __restrict__ out)
{
    __shared__ f16 sAh[64 * LDH], sAl[64 * LDH];
    __shared__ f16 sBh[64 * LDH], sBl[64 * LDH];
    const int tid = threadIdx.x;
    const int bm = blockIdx.x, bn = blockIdx.y;
    const int wave = tid >> 6, lane = tid & 63;
    const int wm = (wave >> 1) * 32, wn = (wave & 1) * 32;
    const int l15 = lane & 15, lq = lane >> 4;

    f32x4 ach[2][2], acx[2][2];
#pragma unroll
    for (int i = 0; i < 2; i++)
#pragma unroll
        for (int j = 0; j < 2; j++) { ach[i][j] = (f32x4)(0.f); acx[i][j] = (f32x4)(0.f); }

    for (int kc = 0; kc < 1024; kc += 32) {
        {
            int e = tid * 8;
            int row = e >> 5, col = e & 31;
            size_t off = (size_t)(bm * 64 + row) * 1024 + kc + col;
            *(uint4*)&sAh[row * LDH + col] = *(const uint4*)(Ah + off);
            *(uint4*)&sAl[row * LDH + col] = *(const uint4*)(Al + off);
        }
#pragma unroll
        for (int l = 0; l < 2; l++) {
            int e = (l * 256 + tid) * 4;
            int crow = e >> 5, col = e & 31;
            float4 g = *(const float4*)(W + (size_t)(bn * 64 + crow) * 1024 + kc + col);
            f16 h0 = (f16)g.x, h1 = (f16)g.y, h2 = (f16)g.z, h3 = (f16)g.w;
            half4 hv = {h0, h1, h2, h3};
            half4 lv = {(f16)((g.x - (float)h0) * SPLIT_SC),
                        (f16)((g.y - (float)h1) * SPLIT_SC),
                        (f16)((g.z - (float)h2) * SPLIT_SC),
                        (f16)((g.w - (float)h3) * SPLIT_SC)};
            *(half4*)&sBh[crow * LDH + col] = hv;
            *(half4*)&sBl[crow * LDH + col] = lv;
        }
        __syncthreads();
        half8 afh[2], afl[2], bfh[2], bfl[2];
#pragma unroll
        for (int mt = 0; mt < 2; mt++) {
            int ro = (wm + mt * 16 + l15) * LDH + lq * 8;
            afh[mt] = *(const half8*)&sAh[ro];
            afl[mt] = *(const half8*)&sAl[ro];
        }
#pragma unroll
        for (int nt = 0; nt < 2; nt++) {
            int ro = (wn + nt * 16 + l15) * LDH + lq * 8;
            bfh[nt] = *(const half8*)&sBh[ro];
            bfl[nt] = *(const half8*)&sBl[ro];
        }
#pragma unroll
        for (int mt = 0; mt < 2; mt++)
#pragma unroll
            for (int nt = 0; nt < 2; nt++) {
                ach[mt][nt] = __builtin_amdgcn_mfma_f32_16x16x32_f16(
                    afh[mt], bfh[nt], ach[mt][nt], 0, 0, 0);
                acx[mt][nt] = __builtin_amdgcn_mfma_f32_16x16x32_f16(
                    afh[mt], bfl[nt], acx[mt][nt], 0, 0, 0);
                acx[mt][nt] = __builtin_amdgcn_mfma_f32_16x16x32_f16(
                    afl[mt], bfh[nt], acx[mt][nt], 0, 0, 0);
            }
        __syncthreads();
    }

#pragma unroll
    for (int mt = 0; mt < 2; mt++) {
#pragma unroll
        for (int nt = 0; nt < 2; nt++) {
            int col = bn * 64 + wn + nt * 16 + l15;
            float bv = bias[col];
#pragma unroll
            for (int rg = 0; rg < 4; rg++) {
                int row = bm * 64 + wm + mt * 16 + lq * 4 + rg;
                float v = ach[mt][nt][rg] + acx[mt][nt][rg] * SPLIT_INV + bv;
                out[(size_t)row * 1024 + col] = fmaxf(v, 0.f);
            }
        }
    }
}

// ---------------------------------------------------------------------------
// final tiny fc: out[b][j] = t[b] . W_fc[j] + b_fc[j], j < 10, fp32 out
// ---------------------------------------------------------------------------
__global__ __launch_bounds__(64) void fc_out(
    const float* __restrict__ tb, const float* __restrict__ Wfc,
    const float* __restrict__ bfc, float* __restrict__ out)
{
    int b = blockIdx.x, lane = threadIdx.x;
    const float* tv = tb + (size_t)b * 1024;
    float p[10];
#pragma unroll
    for (int j = 0; j < 10; j++) p[j] = 0.f;
    for (int k = lane; k < 1024; k += 64) {
        float t = tv[k];
#pragma unroll
        for (int j = 0; j < 10; j++) p[j] += t * Wfc[j * 1024 + k];
    }
#pragma unroll
    for (int j = 0; j < 10; j++) {
#pragma unroll
        for (int o = 32; o > 0; o >>= 1) p[j] += __shfl_xor(p[j], o);
    }
    if (lane == 0) {
#pragma unroll
        for (int j = 0; j < 10; j++) out[b * 10 + j] = p[j] + bfc[j];
    }
}

extern "C" void kernel_launch(void* const* d_in, const int* in_sizes, int n_in,
                              void* d_out, int out_size, void* d_ws, size_t ws_size,
                              hipStream_t stream)
{
    const float* x     = (const float*)d_in[0];
    const float* W_att = (const float*)d_in[1];
    const float* b_att = (const float*)d_in[2];
    const float* W_ih  = (const float*)d_in[3];
    const float* W_hh  = (const float*)d_in[4];
    const float* b_ih  = (const float*)d_in[5];
    const float* b_hh  = (const float*)d_in[6];
    const float* W_fc0 = (const float*)d_in[7];
    const float* b_fc0 = (const float*)d_in[8];
    const float* W_fc  = (const float*)d_in[9];
    const float* b_fc  = (const float*)d_in[10];
    float* out = (float*)d_out;

    // Workspace (~44.5 MB, verified): Wswz | c | h planes x4 | r x2
    char* ws = (char*)d_ws;
    f16*   Wswz   = (f16*)ws;    ws += (size_t)56 * 32 * 16 * 512 * 2;  // 29.36 MB
    float* c_f32  = (float*)ws;  ws += (size_t)1024 * 1024 * 4;         // 4 MB
    f16*   h_hi0  = (f16*)ws;    ws += (size_t)1024 * 1024 * 2;
    f16*   h_hi1  = (f16*)ws;    ws += (size_t)1024 * 1024 * 2;
    f16*   h_lo0  = (f16*)ws;    ws += (size_t)1024 * 1024 * 2;
    f16*   h_lo1  = (f16*)ws;    ws += (size_t)1024 * 1024 * 2;
    f16*   r_hi   = (f16*)ws;    ws += (size_t)1024 * 768 * 2;
    f16*   r_lo   = (f16*)ws;    ws += (size_t)1024 * 768 * 2;
    float* t_f32  = c_f32;  // overlay: c dead after last gates_lstm
    f16* h_hi[2] = {h_hi0, h_hi1};
    f16* h_lo[2] = {h_lo0, h_lo1};

    hipMemsetAsync(c_f32, 0, (size_t)1024 * 1024 * 4, stream);
    hipMemsetAsync(h_hi0, 0, (size_t)1024 * 1024 * 2, stream);
    hipMemsetAsync(h_lo0, 0, (size_t)1024 * 1024 * 2, stream);

    swz_w<<<56 * 32, 256, 0, stream>>>(W_ih, W_hh, Wswz);

    for (int t = 0; t < 16; t++) {
        int rb = t & 1, wb = 1 - rb;
        att_glimpse<<<dim3(1024, 3), 256, 0, stream>>>(
            h_hi[rb], h_lo[rb], W_att, b_att, x, r_hi, r_lo);
        gates_lstm<<<1024, 256, 0, stream>>>(
            r_hi, r_lo, h_hi[rb], h_lo[rb], Wswz, b_ih, b_hh,
            c_f32, h_hi[wb], h_lo[wb]);
    }
    fc0_gemm<<<dim3(16, 16), 256, 0, stream>>>(
        h_hi[0], h_lo[0], W_fc0, b_fc0, t_f32);
    fc_out<<<1024, 64, 0, stream>>>(t_f32, W_fc, b_fc, out);
}

// Round 14
// 1586.258 us; speedup vs baseline: 1.0483x; 1.0483x over previous
//
#include <hip/hip_runtime.h>

typedef unsigned short u16;
typedef unsigned int u32;
typedef _Float16 f16;
typedef _Float16 half8 __attribute__((ext_vector_type(8)));
typedef _Float16 half4 __attribute__((ext_vector_type(4)));
typedef float f32x4 __attribute__((ext_vector_type(4)));

#define SPLIT_SC 2048.0f
#define SPLIT_INV (1.0f / 2048.0f)

__device__ __forceinline__ float sigf(float x) { return 1.0f / (1.0f + expf(-x)); }

// A-operand fragment address for mfma_16x16x32_f16: element (row, k) lives at
// ((k>>5)*64 + row>>4)*512 + (((k&31)>>3)*16 + (row&15))*8 + (k&7)
__device__ __forceinline__ size_t fragA(int row, int k) {
    return ((size_t)((k >> 5) * 64 + (row >> 4))) * 512
         + (size_t)((((k & 31) >> 3) << 4) + (row & 15)) * 8 + (k & 7);
}

// ---------------------------------------------------------------------------
// Fused attention-params + filterbank + glimpse, v5.
// Same as round-10 verified v4 except: h_lo read from fragment layout,
// r_lo written in fragment layout (for gates' direct A-lo VMEM loads).
// ---------------------------------------------------------------------------
__global__ __launch_bounds__(256) void att_glimpse(
    const f16* __restrict__ h_hi, const f16* __restrict__ h_lof,
    const float* __restrict__ Watt, const float* __restrict__ batt,
    const float* __restrict__ x,
    f16* __restrict__ r_hi, f16* __restrict__ r_lof)
{
    __shared__ float simg[64 * 64];      // 16 KB, this channel, [y][a]
    __shared__ float sFx[16 * 68];       // [xo][a], stride 68
    __shared__ float sFyT[64 * 20];      // [y][n],  stride 20
    __shared__ float stmp[16 * 68];      // [n][a],  stride 68
    __shared__ float sred[4 * 5];
    __shared__ float spar[8];

    const int b = blockIdx.x, c = blockIdx.y, tid = threadIdx.x;
    const int lane = tid & 63, wave = tid >> 6;

    {
        const float4* src = (const float4*)(x + (size_t)b * 12288 + c * 4096);
        float4* dst = (float4*)simg;
        for (int i = tid; i < 1024; i += 256) dst[i] = src[i];
    }

    float p[5] = {0.f, 0.f, 0.f, 0.f, 0.f};
    {
        const f16* hh = h_hi + (size_t)b * 1024;
        for (int k = tid; k < 1024; k += 256) {
            float hv = (float)hh[k] + (float)h_lof[fragA(b, k)] * SPLIT_INV;
#pragma unroll
            for (int j = 0; j < 5; j++) p[j] += hv * Watt[j * 1024 + k];
        }
#pragma unroll
        for (int j = 0; j < 5; j++) {
#pragma unroll
            for (int o = 32; o > 0; o >>= 1) p[j] += __shfl_xor(p[j], o);
        }
        if (lane == 0) {
#pragma unroll
            for (int j = 0; j < 5; j++) sred[wave * 5 + j] = p[j];
        }
    }
    __syncthreads();
    if (tid == 0) {
        float q[5];
#pragma unroll
        for (int j = 0; j < 5; j++)
            q[j] = sred[j] + sred[5 + j] + sred[10 + j] + sred[15 + j] + batt[j];
        float q2 = fminf(fmaxf(q[2], -60.f), 60.f);
        float q3 = fminf(fmaxf(q[3], -60.f), 60.f);
        float q4 = fminf(fmaxf(q[4], -60.f), 60.f);
        spar[0] = 32.5f * (q[0] + 1.0f);          // gx
        spar[1] = 32.5f * (q[1] + 1.0f);          // gy
        spar[2] = 0.5f * expf(-q2);               // 1/(2*sigma2)
        spar[3] = 4.2f * expf(q3);                // delta
        spar[4] = expf(q4);                       // gamma
    }
    __syncthreads();
    const float gx = spar[0], gy = spar[1], inv2s2 = spar[2], dl = spar[3],
                gamma = spar[4];

    {
        const float af = (float)lane;
#pragma unroll
        for (int i = 0; i < 4; i++) {
            int n = wave + i * 4;
            float nn = (float)n - 8.5f;
            float mux = gx + nn * dl;
            float ex = af - mux;
            float vx = expf(-ex * ex * inv2s2);
            float sx = vx;
#pragma unroll
            for (int o = 32; o > 0; o >>= 1) sx += __shfl_xor(sx, o);
            sFx[n * 68 + lane] = vx / (sx + 1e-8f);

            float muy = gy + nn * dl;
            float ey = af - muy;
            float vy = expf(-ey * ey * inv2s2);
            float sy = vy;
#pragma unroll
            for (int o = 32; o > 0; o >>= 1) sy += __shfl_xor(sy, o);
            sFyT[lane * 20 + n] = vy / (sy + 1e-8f);   // transposed [y][n]
        }
    }
    __syncthreads();

    // stage 1 (all 4 waves): tmp[n][a] = sum_y Fy[n][y] * img[y][a]
    {
        const int n4 = wave, ysub = lane >> 4, a4 = lane & 15;
        f32x4 acc[4];
#pragma unroll
        for (int j = 0; j < 4; j++) acc[j] = (f32x4)(0.f);
        for (int yy = 0; yy < 16; yy++) {
            int y = ysub * 16 + yy;
            float4 im = *(const float4*)(simg + y * 64 + a4 * 4);
            float4 fy = *(const float4*)(sFyT + y * 20 + n4 * 4);
            f32x4 iv = {im.x, im.y, im.z, im.w};
            acc[0] += fy.x * iv;
            acc[1] += fy.y * iv;
            acc[2] += fy.z * iv;
            acc[3] += fy.w * iv;
        }
#pragma unroll
        for (int j = 0; j < 4; j++) {
#pragma unroll
            for (int o = 16; o <= 32; o <<= 1) {
                acc[j].x += __shfl_xor(acc[j].x, o);
                acc[j].y += __shfl_xor(acc[j].y, o);
                acc[j].z += __shfl_xor(acc[j].z, o);
                acc[j].w += __shfl_xor(acc[j].w, o);
            }
        }
        if (ysub == 0) {
#pragma unroll
            for (int j = 0; j < 4; j++)
                *(f32x4*)(stmp + (n4 * 4 + j) * 68 + a4 * 4) = acc[j];
        }
    }
    __syncthreads();

    {
        const int n = tid >> 4, xo = tid & 15;
        const float* tp = stmp + n * 68;
        const float* fx = sFx + xo * 68;
        float s = 0.f;
        for (int a = 0; a < 64; a += 4) {
            float4 t4 = *(const float4*)(tp + a);
            float4 x4 = *(const float4*)(fx + a);
            s += t4.x * x4.x + t4.y * x4.y + t4.z * x4.z + t4.w * x4.w;
        }
        float v = s * gamma;
        f16 hi = (f16)v;
        int k = c * 256 + tid;
        r_hi[(size_t)b * 768 + k] = hi;
        r_lof[fragA(b, k)] = (f16)((v - (float)hi) * SPLIT_SC);
    }
}

// ---------------------------------------------------------------------------
// W pre-swizzle v2 (round-12 verified): gate = (c&1)*2 + (l15>>3),
// u_local = (c>>1)*8 + (l15&7) -> lane pairs (l15, l15^8) hold all 4 gates.
// ---------------------------------------------------------------------------
__global__ __launch_bounds__(256) void swz_w(
    const float* __restrict__ W1, const float* __restrict__ W2,
    f16* __restrict__ out)
{
    const int kc = blockIdx.x >> 5, bn = blockIdx.x & 31;
    for (int t = threadIdx.x; t < 512; t += 256) {
        int c = t >> 6, lane = t & 63, l15 = lane & 15, lq = lane >> 4;
        int gate = ((c & 1) << 1) + (l15 >> 3);
        int ul   = ((c >> 1) << 3) + (l15 & 7);
        int wrow = gate * 1024 + bn * 32 + ul;
        const float* src;
        if (kc < 24) src = W1 + (size_t)wrow * 768 + kc * 32 + lq * 8;
        else         src = W2 + (size_t)wrow * 1024 + (kc - 24) * 32 + lq * 8;
        float4 g0 = *(const float4*)src;
        float4 g1 = *(const float4*)(src + 4);
        float gv[8] = {g0.x, g0.y, g0.z, g0.w, g1.x, g1.y, g1.z, g1.w};
        half8 hv, lv;
#pragma unroll
        for (int j = 0; j < 8; j++) {
            f16 h = (f16)gv[j];
            hv[j] = h;
            lv[j] = (f16)((gv[j] - (float)h) * SPLIT_SC);
        }
        size_t base = ((size_t)(kc * 32 + bn) * 16 + c * 2) * 512 + (size_t)lane * 8;
        *(half8*)(out + base) = hv;
        *(half8*)(out + base + 512) = lv;
    }
}

// ---------------------------------------------------------------------------
// Fused gates GEMM + LSTM pointwise, v9.
// v7 shape (64x128 tile, grid 512 = 2 blk/CU, wave = 4 m-tiles x 2 c-tiles,
// disjoint B) but A-lo plane moved OUT of LDS: loaded as coalesced VMEM
// fragment loads (register dbuf like B).  LDS carries A-hi only ->
// LDS-pipe ~halved (the measured v7 binder); VMEM takes the slack.
// Bit-identical accumulation order to v7/v12.
// ---------------------------------------------------------------------------
#define LDH 40   // A LDS row stride in f16 elems (80 B)

__global__ __launch_bounds__(256, 2) void gates_lstm(
    const f16* __restrict__ A1h, const f16* __restrict__ A1lf,  // r: row-major hi, frag lo
    const f16* __restrict__ A2h, const f16* __restrict__ A2lf,  // h: row-major hi, frag lo
    const f16* __restrict__ Wswz,
    const float* __restrict__ b1, const float* __restrict__ b2,
    float* __restrict__ cst,
    f16* __restrict__ Hh, f16* __restrict__ Hlf)
{
    __shared__ f16 sA[2][64 * LDH];      // A-hi only, dbuf: 10.25 KB
    const int tid = threadIdx.x;
    const int kb = blockIdx.x;           // 0..511
    const int xcd = kb & 7, jb = kb >> 3;
    const int bn = xcd * 4 + (jb & 3);   // 0..31
    const int bm = jb >> 2;              // 0..15
    const int wave = tid >> 6, lane = tid & 63;
    const int cbase = wave * 2;          // disjoint ctile pair per wave
    const int l15 = lane & 15, lq = lane >> 4;
    const int arow = tid >> 2, acol = (tid & 3) * 8;   // A-hi stage: 1 uint4/thread

    f32x4 ah[4][2], al[4][2];
#pragma unroll
    for (int i = 0; i < 4; i++)
#pragma unroll
        for (int j = 0; j < 2; j++) { ah[i][j] = (f32x4)(0.f); al[i][j] = (f32x4)(0.f); }

    // prologue: stage A-hi(0) into buf0; load B(0) and A-lo(0) fragments
    {
        size_t aoff = (size_t)(bm * 64 + arow) * 768 + acol;
        *(uint4*)&sA[0][arow * LDH + acol] = *(const uint4*)(A1h + aoff);
    }
    half8 Bc[4], Alc[4];
    {
        const f16* wb = Wswz + (size_t)bn * 16 * 512 + (size_t)lane * 8;
#pragma unroll
        for (int nt = 0; nt < 2; nt++) {
            Bc[nt * 2]     = *(const half8*)(wb + (cbase + nt) * 1024);
            Bc[nt * 2 + 1] = *(const half8*)(wb + (cbase + nt) * 1024 + 512);
        }
        const f16* pa = A1lf + (size_t)(bm * 4) * 512 + (size_t)lane * 8;
#pragma unroll
        for (int mt = 0; mt < 4; mt++)
            Alc[mt] = *(const half8*)(pa + mt * 512);
    }

#pragma unroll 2
    for (int i = 0; i < 56; ++i) {
        const int cur = i & 1;
        __syncthreads();                 // buf[cur] ready, prev reads drained
        const int kn = (i + 1 < 56) ? i + 1 : 55;
        // ---- prefetch A-hi(kn) to regs ----
        const f16 *pah; int astr, ako;
        const f16 *palf; size_t abase;
        if (kn < 24) { pah = A1h; astr = 768;  ako = kn * 32;
                       palf = A1lf; abase = (size_t)(kn * 64 + bm * 4) * 512; }
        else         { pah = A2h; astr = 1024; ako = (kn - 24) * 32;
                       palf = A2lf; abase = (size_t)((kn - 24) * 64 + bm * 4) * 512; }
        uint4 vh = *(const uint4*)(pah + (size_t)(bm * 64 + arow) * astr + ako + acol);
        // ---- prefetch B(kn) + A-lo(kn) fragments ----
        half8 Bn[4], Aln[4];
        {
            const f16* wb = Wswz + (size_t)(kn * 32 + bn) * 16 * 512 + (size_t)lane * 8;
#pragma unroll
            for (int nt = 0; nt < 2; nt++) {
                Bn[nt * 2]     = *(const half8*)(wb + (cbase + nt) * 1024);
                Bn[nt * 2 + 1] = *(const half8*)(wb + (cbase + nt) * 1024 + 512);
            }
            const f16* pa = palf + (size_t)lane * 8;
#pragma unroll
            for (int mt = 0; mt < 4; mt++)
                Aln[mt] = *(const half8*)(pa + abase + mt * 512);
        }
        // ---- compute on buf[cur]: 4 m-tiles x 2 c-tiles ----
        half8 afh[4];
#pragma unroll
        for (int mt = 0; mt < 4; mt++)
            afh[mt] = *(const half8*)&sA[cur][(mt * 16 + l15) * LDH + lq * 8];
#pragma unroll
        for (int mt = 0; mt < 4; mt++)
#pragma unroll
            for (int nt = 0; nt < 2; nt++) {
                ah[mt][nt] = __builtin_amdgcn_mfma_f32_16x16x32_f16(
                    afh[mt], Bc[nt * 2], ah[mt][nt], 0, 0, 0);
                al[mt][nt] = __builtin_amdgcn_mfma_f32_16x16x32_f16(
                    afh[mt], Bc[nt * 2 + 1], al[mt][nt], 0, 0, 0);
                al[mt][nt] = __builtin_amdgcn_mfma_f32_16x16x32_f16(
                    Alc[mt], Bc[nt * 2], al[mt][nt], 0, 0, 0);
            }
        // ---- write prefetched A-hi into the other buffer, rotate regs ----
        const int nxt = cur ^ 1;
        *(uint4*)&sA[nxt][arow * LDH + acol] = vh;
#pragma unroll
        for (int q = 0; q < 4; q++) { Bc[q] = Bn[q]; Alc[q] = Aln[q]; }
    }

    // epilogue (v7-verified): lane holds gates {g0, g0+2}, g0 = l15>>3, at
    // u = bn*32 + wave*8 + (l15&7); partner lane l15^8 holds the other pair.
    const int g0 = l15 >> 3;
    const int u = bn * 32 + wave * 8 + (l15 & 7);
    const float bv0 = b1[g0 * 1024 + u] + b2[g0 * 1024 + u];
    const float bv1 = b1[(g0 + 2) * 1024 + u] + b2[(g0 + 2) * 1024 + u];
#pragma unroll
    for (int mt = 0; mt < 4; mt++) {
#pragma unroll
        for (int rg = 0; rg < 4; rg++) {
            int row = bm * 64 + mt * 16 + lq * 4 + rg;
            size_t idx = (size_t)row * 1024 + u;
            float mine0 = ah[mt][0][rg] + al[mt][0][rg] * SPLIT_INV + bv0;
            float mine1 = ah[mt][1][rg] + al[mt][1][rg] * SPLIT_INV + bv1;
            float oth0 = __shfl_xor(mine0, 8);
            float oth1 = __shfl_xor(mine1, 8);
            float gi = (g0 == 0) ? mine0 : oth0;
            float gg = (g0 == 0) ? mine1 : oth1;
            float gf = (g0 == 0) ? oth0 : mine0;
            float go = (g0 == 0) ? oth1 : mine1;
            if (g0 == 0) {
                float cn = sigf(gf) * cst[idx] + sigf(gi) * tanhf(gg);
                float hn = sigf(go) * tanhf(cn);
                cst[idx] = cn;
                f16 hh = (f16)hn;
                Hh[idx] = hh;
                Hlf[fragA(row, u)] = (f16)((hn - (float)hh) * SPLIT_SC);
            }
        }
    }
}

// ---------------------------------------------------------------------------
// fc0 v4: 64x64 tiles, grid (16,16); A-hi via LDS, A-lo via direct frag loads.
// ---------------------------------------------------------------------------
__global__ __launch_bounds__(256) void fc0_gemm(
    const f16* __restrict__ Ah, const f16* __restrict__ Alf,
    const float* __restrict__ W, const float* __restrict__ bias,
    float* __restrict__ out)
{
    __shared__ f16 sAh[64 * LDH];
    __shared__ f16 sBh[64 * LDH], sBl[64 * LDH];
    const int tid = threadIdx.x;
    const int bm = blockIdx.x, bn = blockIdx.y;
    const int wave = tid >> 6, lane = tid & 63;
    const int wm = (wave >> 1) * 32, wn = (wave & 1) * 32;
    const int l15 = lane & 15, lq = lane >> 4;

    f32x4 ach[2][2], acx[2][2];
#pragma unroll
    for (int i = 0; i < 2; i++)
#pragma unroll
        for (int j = 0; j < 2; j++) { ach[i][j] = (f32x4)(0.f); acx[i][j] = (f32x4)(0.f); }

    for (int kc = 0; kc < 1024; kc += 32) {
        {
            int e = tid * 8;
            int row = e >> 5, col = e & 31;
            size_t off = (size_t)(bm * 64 + row) * 1024 + kc + col;
            *(uint4*)&sAh[row * LDH + col] = *(const uint4*)(Ah + off);
        }
#pragma unroll
        for (int l = 0; l < 2; l++) {
            int e = (l * 256 + tid) * 4;
            int crow = e >> 5, col = e & 31;
            float4 g = *(const float4*)(W + (size_t)(bn * 64 + crow) * 1024 + kc + col);
            f16 h0 = (f16)g.x, h1 = (f16)g.y, h2 = (f16)g.z, h3 = (f16)g.w;
            half4 hv = {h0, h1, h2, h3};
            half4 lv = {(f16)((g.x - (float)h0) * SPLIT_SC),
                        (f16)((g.y - (float)h1) * SPLIT_SC),
                        (f16)((g.z - (float)h2) * SPLIT_SC),
                        (f16)((g.w - (float)h3) * SPLIT_SC)};
            *(half4*)&sBh[crow * LDH + col] = hv;
            *(half4*)&sBl[crow * LDH + col] = lv;
        }
        __syncthreads();
        half8 afh[2], afl[2], bfh[2], bfl[2];
#pragma unroll
        for (int mt = 0; mt < 2; mt++) {
            afh[mt] = *(const half8*)&sAh[(wm + mt * 16 + l15) * LDH + lq * 8];
            int rt = bm * 4 + (wave >> 1) * 2 + mt;
            afl[mt] = *(const half8*)(Alf + (size_t)((kc >> 5) * 64 + rt) * 512
                                          + (size_t)lane * 8);
        }
#pragma unroll
        for (int nt = 0; nt < 2; nt++) {
            int ro = (wn + nt * 16 + l15) * LDH + lq * 8;
            bfh[nt] = *(const half8*)&sBh[ro];
            bfl[nt] = *(const half8*)&sBl[ro];
        }
#pragma unroll
        for (int mt = 0; mt < 2; mt++)
#pragma unroll
            for (int nt = 0; nt < 2; nt++) {
                ach[mt][nt] = __builtin_amdgcn_mfma_f32_16x16x32_f16(
                    afh[mt], bfh[nt], ach[mt][nt], 0, 0, 0);
                acx[mt][nt] = __builtin_amdgcn_mfma_f32_16x16x32_f16(
                    afh[mt], bfl[nt], acx[mt][nt], 0, 0, 0);
                acx[mt][nt] = __builtin_amdgcn_mfma_f32_16x16x32_f16(
                    afl[mt], bfh[nt], acx[mt][nt], 0, 0, 0);
            }
        __syncthreads();
    }

#pragma unroll
    for (int mt = 0; mt < 2; mt++) {
#pragma unroll
        for (int nt = 0; nt < 2; nt++) {
            int col = bn * 64 + wn + nt * 16 + l15;
            float bv = bias[col];
#pragma unroll
            for (int rg = 0; rg < 4; rg++) {
                int row = bm * 64 + wm + mt * 16 + lq * 4 + rg;
                float v = ach[mt][nt][rg] + acx[mt][nt][rg] * SPLIT_INV + bv;
                out[(size_t)row * 1024 + col] = fmaxf(v, 0.f);
            }
        }
    }
}

// ---------------------------------------------------------------------------
// final tiny fc: out[b][j] = t[b] . W_fc[j] + b_fc[j], j < 10, fp32 out
// ---------------------------------------------------------------------------
__global__ __launch_bounds__(64) void fc_out(
    const float* __restrict__ tb, const float* __restrict__ Wfc,
    const float* __restrict__ bfc, float* __restrict__ out)
{
    int b = blockIdx.x, lane = threadIdx.x;
    const float* tv = tb + (size_t)b * 1024;
    float p[10];
#pragma unroll
    for (int j = 0; j < 10; j++) p[j] = 0.f;
    for (int k = lane; k < 1024; k += 64) {
        float t = tv[k];
#pragma unroll
        for (int j = 0; j < 10; j++) p[j] += t * Wfc[j * 1024 + k];
    }
#pragma unroll
    for (int j = 0; j < 10; j++) {
#pragma unroll
        for (int o = 32; o > 0; o >>= 1) p[j] += __shfl_xor(p[j], o);
    }
    if (lane == 0) {
#pragma unroll
        for (int j = 0; j < 10; j++) out[b * 10 + j] = p[j] + bfc[j];
    }
}

extern "C" void kernel_launch(void* const* d_in, const int* in_sizes, int n_in,
                              void* d_out, int out_size, void* d_ws, size_t ws_size,
                              hipStream_t stream)
{
    const float* x     = (const float*)d_in[0];
    const float* W_att = (const float*)d_in[1];
    const float* b_att = (const float*)d_in[2];
    const float* W_ih  = (const float*)d_in[3];
    const float* W_hh  = (const float*)d_in[4];
    const float* b_ih  = (const float*)d_in[5];
    const float* b_hh  = (const float*)d_in[6];
    const float* W_fc0 = (const float*)d_in[7];
    const float* b_fc0 = (const float*)d_in[8];
    const float* W_fc  = (const float*)d_in[9];
    const float* b_fc  = (const float*)d_in[10];
    float* out = (float*)d_out;

    // Workspace (~44.4 MB, verified size class):
    // Wswz | c | h_hi x2 (row-major) | h_lof x2 (frag) | r_hi | r_lof (frag)
    char* ws = (char*)d_ws;
    f16*   Wswz   = (f16*)ws;    ws += (size_t)56 * 32 * 16 * 512 * 2;  // 29.36 MB
    float* c_f32  = (float*)ws;  ws += (size_t)1024 * 1024 * 4;         // 4 MB
    f16*   h_hi0  = (f16*)ws;    ws += (size_t)1024 * 1024 * 2;
    f16*   h_hi1  = (f16*)ws;    ws += (size_t)1024 * 1024 * 2;
    f16*   h_lof0 = (f16*)ws;    ws += (size_t)32 * 64 * 512 * 2;       // 2 MB frag
    f16*   h_lof1 = (f16*)ws;    ws += (size_t)32 * 64 * 512 * 2;       // 2 MB frag
    f16*   r_hi   = (f16*)ws;    ws += (size_t)1024 * 768 * 2;
    f16*   r_lof  = (f16*)ws;    ws += (size_t)24 * 64 * 512 * 2;       // 1.5 MB frag
    float* t_f32  = c_f32;  // overlay: c dead after last gates_lstm
    f16* h_hi[2]  = {h_hi0, h_hi1};
    f16* h_lof[2] = {h_lof0, h_lof1};

    hipMemsetAsync(c_f32, 0, (size_t)1024 * 1024 * 4, stream);
    hipMemsetAsync(h_hi0, 0, (size_t)1024 * 1024 * 2, stream);
    hipMemsetAsync(h_lof0, 0, (size_t)32 * 64 * 512 * 2, stream);

    swz_w<<<56 * 32, 256, 0, stream>>>(W_ih, W_hh, Wswz);

    for (int t = 0; t < 16; t++) {
        int rb = t & 1, wb = 1 - rb;
        att_glimpse<<<dim3(1024, 3), 256, 0, stream>>>(
            h_hi[rb], h_lof[rb], W_att, b_att, x, r_hi, r_lof);
        gates_lstm<<<512, 256, 0, stream>>>(
            r_hi, r_lof, h_hi[rb], h_lof[rb], Wswz, b_ih, b_hh,
            c_f32, h_hi[wb], h_lof[wb]);
    }
    fc0_gemm<<<dim3(16, 16), 256, 0, stream>>>(
        h_hi[0], h_lof[0], W_fc0, b_fc0, t_f32);
    fc_out<<<1024, 64, 0, stream>>>(t_f32, W_fc, b_fc, out);
}

// Round 15
// 1401.216 us; speedup vs baseline: 1.1867x; 1.1321x over previous
//
#include <hip/hip_runtime.h>

typedef unsigned short u16;
typedef unsigned int u32;
typedef _Float16 f16;
typedef _Float16 half8 __attribute__((ext_vector_type(8)));
typedef _Float16 half4 __attribute__((ext_vector_type(4)));
typedef float f32x4 __attribute__((ext_vector_type(4)));

#define SPLIT_SC 2048.0f
#define SPLIT_INV (1.0f / 2048.0f)

__device__ __forceinline__ float sigf(float x) { return 1.0f / (1.0f + expf(-x)); }

// ---------------------------------------------------------------------------
// Fused attention-params + filterbank + glimpse, v6.
// Grid 1024 (one block per batch item); channels processed in an in-block
// loop so phase A (h.Watt) and the exp-heavy filterbank run ONCE instead of
// 3x (they were per-channel-redundant in the grid-(1024,3) version).
// Numerics/accumulation order per output identical to round-12 (verified).
// ---------------------------------------------------------------------------
__global__ __launch_bounds__(256) void att_glimpse(
    const f16* __restrict__ h_hi, const f16* __restrict__ h_lo,
    const float* __restrict__ Watt, const float* __restrict__ batt,
    const float* __restrict__ x,
    f16* __restrict__ r_hi, f16* __restrict__ r_lo)
{
    __shared__ float simg[64 * 64];      // 16 KB, one channel, [y][a]
    __shared__ float sFx[16 * 68];       // [xo][a], stride 68
    __shared__ float sFyT[64 * 20];      // [y][n],  stride 20
    __shared__ float stmp[16 * 68];      // [n][a],  stride 68
    __shared__ float sred[4 * 5];
    __shared__ float spar[8];

    const int b = blockIdx.x, tid = threadIdx.x;
    const int lane = tid & 63, wave = tid >> 6;

    // phase A: p = h[b] @ Watt^T + batt (5 dots of length 1024), fp32
    float p[5] = {0.f, 0.f, 0.f, 0.f, 0.f};
    {
        const f16* hh = h_hi + (size_t)b * 1024;
        const f16* hl = h_lo + (size_t)b * 1024;
        for (int k = tid; k < 1024; k += 256) {
            float hv = (float)hh[k] + (float)hl[k] * SPLIT_INV;
#pragma unroll
            for (int j = 0; j < 5; j++) p[j] += hv * Watt[j * 1024 + k];
        }
#pragma unroll
        for (int j = 0; j < 5; j++) {
#pragma unroll
            for (int o = 32; o > 0; o >>= 1) p[j] += __shfl_xor(p[j], o);
        }
        if (lane == 0) {
#pragma unroll
            for (int j = 0; j < 5; j++) sred[wave * 5 + j] = p[j];
        }
    }
    __syncthreads();
    if (tid == 0) {
        float q[5];
#pragma unroll
        for (int j = 0; j < 5; j++)
            q[j] = sred[j] + sred[5 + j] + sred[10 + j] + sred[15 + j] + batt[j];
        float q2 = fminf(fmaxf(q[2], -60.f), 60.f);
        float q3 = fminf(fmaxf(q[3], -60.f), 60.f);
        float q4 = fminf(fmaxf(q[4], -60.f), 60.f);
        spar[0] = 32.5f * (q[0] + 1.0f);          // gx
        spar[1] = 32.5f * (q[1] + 1.0f);          // gy
        spar[2] = 0.5f * expf(-q2);               // 1/(2*sigma2)
        spar[3] = 4.2f * expf(q3);                // delta
        spar[4] = expf(q4);                       // gamma
    }
    __syncthreads();
    const float gx = spar[0], gy = spar[1], inv2s2 = spar[2], dl = spar[3],
                gamma = spar[4];

    // phase B: filterbank (once).  wave w: n = w, w+4, w+8, w+12; lane = px
    {
        const float af = (float)lane;
#pragma unroll
        for (int i = 0; i < 4; i++) {
            int n = wave + i * 4;
            float nn = (float)n - 8.5f;
            float mux = gx + nn * dl;
            float ex = af - mux;
            float vx = expf(-ex * ex * inv2s2);
            float sx = vx;
#pragma unroll
            for (int o = 32; o > 0; o >>= 1) sx += __shfl_xor(sx, o);
            sFx[n * 68 + lane] = vx / (sx + 1e-8f);

            float muy = gy + nn * dl;
            float ey = af - muy;
            float vy = expf(-ey * ey * inv2s2);
            float sy = vy;
#pragma unroll
            for (int o = 32; o > 0; o >>= 1) sy += __shfl_xor(sy, o);
            sFyT[lane * 20 + n] = vy / (sy + 1e-8f);   // transposed [y][n]
        }
    }

    // channel loop: stage img -> stage1 -> stage2, reusing simg/stmp
    for (int c = 0; c < 3; c++) {
        __syncthreads();   // sFx/sFyT ready (c=0); stmp reads done (c>0)
        {
            const float4* src = (const float4*)(x + (size_t)b * 12288 + c * 4096);
            float4* dst = (float4*)simg;
            for (int i = tid; i < 1024; i += 256) dst[i] = src[i];
        }
        __syncthreads();

        // stage 1 (all 4 waves): tmp[n][a] = sum_y Fy[n][y] * img[y][a]
        {
            const int n4 = wave, ysub = lane >> 4, a4 = lane & 15;
            f32x4 acc[4];
#pragma unroll
            for (int j = 0; j < 4; j++) acc[j] = (f32x4)(0.f);
            for (int yy = 0; yy < 16; yy++) {
                int y = ysub * 16 + yy;
                float4 im = *(const float4*)(simg + y * 64 + a4 * 4);
                float4 fy = *(const float4*)(sFyT + y * 20 + n4 * 4);
                f32x4 iv = {im.x, im.y, im.z, im.w};
                acc[0] += fy.x * iv;
                acc[1] += fy.y * iv;
                acc[2] += fy.z * iv;
                acc[3] += fy.w * iv;
            }
#pragma unroll
            for (int j = 0; j < 4; j++) {
#pragma unroll
                for (int o = 16; o <= 32; o <<= 1) {
                    acc[j].x += __shfl_xor(acc[j].x, o);
                    acc[j].y += __shfl_xor(acc[j].y, o);
                    acc[j].z += __shfl_xor(acc[j].z, o);
                    acc[j].w += __shfl_xor(acc[j].w, o);
                }
            }
            if (ysub == 0) {
#pragma unroll
                for (int j = 0; j < 4; j++)
                    *(f32x4*)(stmp + (n4 * 4 + j) * 68 + a4 * 4) = acc[j];
            }
        }
        __syncthreads();

        // stage 2: r[n][xo] = gamma * sum_a tmp[n][a] * Fx[xo][a]
        {
            const int n = tid >> 4, xo = tid & 15;
            const float* tp = stmp + n * 68;
            const float* fx = sFx + xo * 68;
            float s = 0.f;
            for (int a = 0; a < 64; a += 4) {
                float4 t4 = *(const float4*)(tp + a);
                float4 x4 = *(const float4*)(fx + a);
                s += t4.x * x4.x + t4.y * x4.y + t4.z * x4.z + t4.w * x4.w;
            }
            float v = s * gamma;
            f16 hi = (f16)v;
            size_t idx = (size_t)b * 768 + c * 256 + tid;
            r_hi[idx] = hi;
            r_lo[idx] = (f16)((v - (float)hi) * SPLIT_SC);
        }
    }
}

// ---------------------------------------------------------------------------
// W pre-swizzle v2 (round-12 verified): gate = (c&1)*2 + (l15>>3),
// u_local = (c>>1)*8 + (l15&7) -> lane pairs (l15, l15^8) hold all 4 gates.
// ---------------------------------------------------------------------------
__global__ __launch_bounds__(256) void swz_w(
    const float* __restrict__ W1, const float* __restrict__ W2,
    f16* __restrict__ out)
{
    const int kc = blockIdx.x >> 5, bn = blockIdx.x & 31;
    for (int t = threadIdx.x; t < 512; t += 256) {
        int c = t >> 6, lane = t & 63, l15 = lane & 15, lq = lane >> 4;
        int gate = ((c & 1) << 1) + (l15 >> 3);
        int ul   = ((c >> 1) << 3) + (l15 & 7);
        int wrow = gate * 1024 + bn * 32 + ul;
        const float* src;
        if (kc < 24) src = W1 + (size_t)wrow * 768 + kc * 32 + lq * 8;
        else         src = W2 + (size_t)wrow * 1024 + (kc - 24) * 32 + lq * 8;
        float4 g0 = *(const float4*)src;
        float4 g1 = *(const float4*)(src + 4);
        float gv[8] = {g0.x, g0.y, g0.z, g0.w, g1.x, g1.y, g1.z, g1.w};
        half8 hv, lv;
#pragma unroll
        for (int j = 0; j < 8; j++) {
            f16 h = (f16)gv[j];
            hv[j] = h;
            lv[j] = (f16)((gv[j] - (float)h) * SPLIT_SC);
        }
        size_t base = ((size_t)(kc * 32 + bn) * 16 + c * 2) * 512 + (size_t)lane * 8;
        *(half8*)(out + base) = hv;
        *(half8*)(out + base + 512) = lv;
    }
}

// ---------------------------------------------------------------------------
// Fused gates GEMM + LSTM pointwise, v7 (round-12 verified, 56.5us — best).
// 64x128 tile, grid 512 = 2 blk/CU; wave = 4 m-tiles x 2 c-tiles (disjoint
// B); A LDS dbuf + reg prefetch; 1 barrier/iter; shfl_xor(8) gate epilogue.
// ---------------------------------------------------------------------------
#define LDH 40   // A LDS row stride in f16 elems (80 B)

__global__ __launch_bounds__(256, 2) void gates_lstm(
    const f16* __restrict__ A1h, const f16* __restrict__ A1l,  // r [1024][768]
    const f16* __restrict__ A2h, const f16* __restrict__ A2l,  // h [1024][1024]
    const f16* __restrict__ Wswz,                               // swizzled W
    const float* __restrict__ b1, const float* __restrict__ b2,
    float* __restrict__ cst,
    f16* __restrict__ Hh, f16* __restrict__ Hl)
{
    __shared__ f16 sA[2][2][64 * LDH];   // [buf][plane] 20.5 KB total
    const int tid = threadIdx.x;
    const int kb = blockIdx.x;           // 0..511
    const int xcd = kb & 7, jb = kb >> 3;
    const int bn = xcd * 4 + (jb & 3);   // 0..31
    const int bm = jb >> 2;              // 0..15
    const int wave = tid >> 6, lane = tid & 63;
    const int cbase = wave * 2;          // disjoint ctile pair per wave
    const int l15 = lane & 15, lq = lane >> 4;
    const int arow = tid >> 2, acol = (tid & 3) * 8;

    f32x4 ah[4][2], al[4][2];
#pragma unroll
    for (int i = 0; i < 4; i++)
#pragma unroll
        for (int j = 0; j < 2; j++) { ah[i][j] = (f32x4)(0.f); al[i][j] = (f32x4)(0.f); }

    // prologue: stage A(kc=0) into buf0, load B(kc=0) fragments
    {
        size_t aoff = (size_t)(bm * 64 + arow) * 768 + acol;
        *(uint4*)&sA[0][0][arow * LDH + acol] = *(const uint4*)(A1h + aoff);
        *(uint4*)&sA[0][1][arow * LDH + acol] = *(const uint4*)(A1l + aoff);
    }
    half8 Bc[4];
    {
        const f16* wb = Wswz + (size_t)bn * 16 * 512 + (size_t)lane * 8;
#pragma unroll
        for (int nt = 0; nt < 2; nt++) {
            Bc[nt * 2]     = *(const half8*)(wb + (cbase + nt) * 1024);
            Bc[nt * 2 + 1] = *(const half8*)(wb + (cbase + nt) * 1024 + 512);
        }
    }

#pragma unroll 2
    for (int i = 0; i < 56; ++i) {
        const int cur = i & 1;
        __syncthreads();                 // buf[cur] ready, prev reads drained
        const int kn = (i + 1 < 56) ? i + 1 : 55;
        // ---- prefetch A(kn) to regs ----
        const f16 *pah, *pal; int astr, ako;
        if (kn < 24) { pah = A1h; pal = A1l; astr = 768;  ako = kn * 32; }
        else         { pah = A2h; pal = A2l; astr = 1024; ako = (kn - 24) * 32; }
        size_t aoff = (size_t)(bm * 64 + arow) * astr + ako + acol;
        uint4 vh = *(const uint4*)(pah + aoff);
        uint4 vl = *(const uint4*)(pal + aoff);
        // ---- prefetch B(kn) fragments ----
        half8 Bn[4];
        {
            const f16* wb = Wswz + (size_t)(kn * 32 + bn) * 16 * 512 + (size_t)lane * 8;
#pragma unroll
            for (int nt = 0; nt < 2; nt++) {
                Bn[nt * 2]     = *(const half8*)(wb + (cbase + nt) * 1024);
                Bn[nt * 2 + 1] = *(const half8*)(wb + (cbase + nt) * 1024 + 512);
            }
        }
        // ---- compute on buf[cur] with Bc: 4 m-tiles x 2 c-tiles ----
        half8 afh[4], afl[4];
#pragma unroll
        for (int mt = 0; mt < 4; mt++) {
            int ro = (mt * 16 + l15) * LDH + lq * 8;
            afh[mt] = *(const half8*)&sA[cur][0][ro];
            afl[mt] = *(const half8*)&sA[cur][1][ro];
        }
#pragma unroll
        for (int mt = 0; mt < 4; mt++)
#pragma unroll
            for (int nt = 0; nt < 2; nt++) {
                ah[mt][nt] = __builtin_amdgcn_mfma_f32_16x16x32_f16(
                    afh[mt], Bc[nt * 2], ah[mt][nt], 0, 0, 0);
                al[mt][nt] = __builtin_amdgcn_mfma_f32_16x16x32_f16(
                    afh[mt], Bc[nt * 2 + 1], al[mt][nt], 0, 0, 0);
                al[mt][nt] = __builtin_amdgcn_mfma_f32_16x16x32_f16(
                    afl[mt], Bc[nt * 2], al[mt][nt], 0, 0, 0);
            }
        // ---- write prefetched A into the other buffer, rotate B ----
        const int nxt = cur ^ 1;
        *(uint4*)&sA[nxt][0][arow * LDH + acol] = vh;
        *(uint4*)&sA[nxt][1][arow * LDH + acol] = vl;
#pragma unroll
        for (int q = 0; q < 4; q++) Bc[q] = Bn[q];
    }

    // epilogue: lane holds gates {g0, g0+2} (g0 = l15>>3) at
    // u = bn*32 + wave*8 + (l15&7); partner lane l15^8 holds the other pair.
    const int g0 = l15 >> 3;
    const int u = bn * 32 + wave * 8 + (l15 & 7);
    const float bv0 = b1[g0 * 1024 + u] + b2[g0 * 1024 + u];
    const float bv1 = b1[(g0 + 2) * 1024 + u] + b2[(g0 + 2) * 1024 + u];
#pragma unroll
    for (int mt = 0; mt < 4; mt++) {
#pragma unroll
        for (int rg = 0; rg < 4; rg++) {
            int row = bm * 64 + mt * 16 + lq * 4 + rg;
            size_t idx = (size_t)row * 1024 + u;
            float mine0 = ah[mt][0][rg] + al[mt][0][rg] * SPLIT_INV + bv0;
            float mine1 = ah[mt][1][rg] + al[mt][1][rg] * SPLIT_INV + bv1;
            float oth0 = __shfl_xor(mine0, 8);
            float oth1 = __shfl_xor(mine1, 8);
            // g0==0: mine={i,g}, oth={f,o};  g0==1: mine={f,o}, oth={i,g}
            float gi = (g0 == 0) ? mine0 : oth0;
            float gg = (g0 == 0) ? mine1 : oth1;
            float gf = (g0 == 0) ? oth0 : mine0;
            float go = (g0 == 0) ? oth1 : mine1;
            if (g0 == 0) {
                float cn = sigf(gf) * cst[idx] + sigf(gi) * tanhf(gg);
                float hn = sigf(go) * tanhf(cn);
                cst[idx] = cn;
                f16 hh = (f16)hn;
                Hh[idx] = hh;
                Hl[idx] = (f16)((hn - (float)hh) * SPLIT_SC);
            }
        }
    }
}

// ---------------------------------------------------------------------------
// fc0 v3 (round-10/12 verified): 64x64 tiles, grid (16,16).
// ---------------------------------------------------------------------------
__global__ __launch_bounds__(256) void fc0_gemm(
    const f16* __restrict__ Ah, const f16* __restrict__ Al,
    const float* __restrict__ W, const float* __restrict__ bias,
    float* __restrict__ out)
{
    __shared__ f16 sAh[64 * LDH], sAl[64 * LDH];
    __shared__ f16 sBh[64 * LDH], sBl[64 * LDH];
    const int tid = threadIdx.x;
    const int bm = blockIdx.x, bn = blockIdx.y;
    const int wave = tid >> 6, lane = tid & 63;
    const int wm = (wave >> 1) * 32, wn = (wave & 1) * 32;
    const int l15 = lane & 15, lq = lane >> 4;

    f32x4 ach[2][2], acx[2][2];
#pragma unroll
    for (int i = 0; i < 2; i++)
#pragma unroll
        for (int j = 0; j < 2; j++) { ach[i][j] = (f32x4)(0.f); acx[i][j] = (f32x4)(0.f); }

    for (int kc = 0; kc < 1024; kc += 32) {
        {
            int e = tid * 8;
            int row = e >> 5, col = e & 31;
            size_t off = (size_t)(bm * 64 + row) * 1024 + kc + col;
            *(uint4*)&sAh[row * LDH + col] = *(const uint4*)(Ah + off);
            *(uint4*)&sAl[row * LDH + col] = *(const uint4*)(Al + off);
        }
#pragma unroll
        for (int l = 0; l < 2; l++) {
            int e = (l * 256 + tid) * 4;
            int crow = e >> 5, col = e & 31;
            float4 g = *(const float4*)(W + (size_t)(bn * 64 + crow) * 1024 + kc + col);
            f16 h0 = (f16)g.x, h1 = (f16)g.y, h2 = (f16)g.z, h3 = (f16)g.w;
            half4 hv = {h0, h1, h2, h3};
            half4 lv = {(f16)((g.x - (float)h0) * SPLIT_SC),
                        (f16)((g.y - (float)h1) * SPLIT_SC),
                        (f16)((g.z - (float)h2) * SPLIT_SC),
                        (f16)((g.w - (float)h3) * SPLIT_SC)};
            *(half4*)&sBh[crow * LDH + col] = hv;
            *(half4*)&sBl[crow * LDH + col] = lv;
        }
        __syncthreads();
        half8 afh[2], afl[2], bfh[2], bfl[2];
#pragma unroll
        for (int mt = 0; mt < 2; mt++) {
            int ro = (wm + mt * 16 + l15) * LDH + lq * 8;
            afh[mt] = *(const half8*)&sAh[ro];
            afl[mt] = *(const half8*)&sAl[ro];
        }
#pragma unroll
        for (int nt = 0; nt < 2; nt++) {
            int ro = (wn + nt * 16 + l15) * LDH + lq * 8;
            bfh[nt] = *(const half8*)&sBh[ro];
            bfl[nt] = *(const half8*)&sBl[ro];
        }
#pragma unroll
        for (int mt = 0; mt < 2; mt++)
#pragma unroll
            for (int nt = 0; nt < 2; nt++) {
                ach[mt][nt] = __builtin_amdgcn_mfma_f32_16x16x32_f16(
                    afh[mt], bfh[nt], ach[mt][nt], 0, 0, 0);
                acx[mt][nt] = __builtin_amdgcn_mfma_f32_16x16x32_f16(
                    afh[mt], bfl[nt], acx[mt][nt], 0, 0, 0);
                acx[mt][nt] = __builtin_amdgcn_mfma_f32_16x16x32_f16(
                    afl[mt], bfh[nt], acx[mt][nt], 0, 0, 0);
            }
        __syncthreads();
    }

#pragma unroll
    for (int mt = 0; mt < 2; mt++) {
#pragma unroll
        for (int nt = 0; nt < 2; nt++) {
            int col = bn * 64 + wn + nt * 16 + l15;
            float bv = bias[col];
#pragma unroll
            for (int rg = 0; rg < 4; rg++) {
                int row = bm * 64 + wm + mt * 16 + lq * 4 + rg;
                float v = ach[mt][nt][rg] + acx[mt][nt][rg] * SPLIT_INV + bv;
                out[(size_t)row * 1024 + col] = fmaxf(v, 0.f);
            }
        }
    }
}

// ---------------------------------------------------------------------------
// final tiny fc: out[b][j] = t[b] . W_fc[j] + b_fc[j], j < 10, fp32 out
// ---------------------------------------------------------------------------
__global__ __launch_bounds__(64) void fc_out(
    const float* __restrict__ tb, const float* __restrict__ Wfc,
    const float* __restrict__ bfc, float* __restrict__ out)
{
    int b = blockIdx.x, lane = threadIdx.x;
    const float* tv = tb + (size_t)b * 1024;
    float p[10];
#pragma unroll
    for (int j = 0; j < 10; j++) p[j] = 0.f;
    for (int k = lane; k < 1024; k += 64) {
        float t = tv[k];
#pragma unroll
        for (int j = 0; j < 10; j++) p[j] += t * Wfc[j * 1024 + k];
    }
#pragma unroll
    for (int j = 0; j < 10; j++) {
#pragma unroll
        for (int o = 32; o > 0; o >>= 1) p[j] += __shfl_xor(p[j], o);
    }
    if (lane == 0) {
#pragma unroll
        for (int j = 0; j < 10; j++) out[b * 10 + j] = p[j] + bfc[j];
    }
}

extern "C" void kernel_launch(void* const* d_in, const int* in_sizes, int n_in,
                              void* d_out, int out_size, void* d_ws, size_t ws_size,
                              hipStream_t stream)
{
    const float* x     = (const float*)d_in[0];
    const float* W_att = (const float*)d_in[1];
    const float* b_att = (const float*)d_in[2];
    const float* W_ih  = (const float*)d_in[3];
    const float* W_hh  = (const float*)d_in[4];
    const float* b_ih  = (const float*)d_in[5];
    const float* b_hh  = (const float*)d_in[6];
    const float* W_fc0 = (const float*)d_in[7];
    const float* b_fc0 = (const float*)d_in[8];
    const float* W_fc  = (const float*)d_in[9];
    const float* b_fc  = (const float*)d_in[10];
    float* out = (float*)d_out;

    // Workspace (~44.5 MB, round-12 verified): Wswz | c | h planes x4 | r x2
    char* ws = (char*)d_ws;
    f16*   Wswz   = (f16*)ws;    ws += (size_t)56 * 32 * 16 * 512 * 2;  // 29.36 MB
    float* c_f32  = (float*)ws;  ws += (size_t)1024 * 1024 * 4;         // 4 MB
    f16*   h_hi0  = (f16*)ws;    ws += (size_t)1024 * 1024 * 2;
    f16*   h_hi1  = (f16*)ws;    ws += (size_t)1024 * 1024 * 2;
    f16*   h_lo0  = (f16*)ws;    ws += (size_t)1024 * 1024 * 2;
    f16*   h_lo1  = (f16*)ws;    ws += (size_t)1024 * 1024 * 2;
    f16*   r_hi   = (f16*)ws;    ws += (size_t)1024 * 768 * 2;
    f16*   r_lo   = (f16*)ws;    ws += (size_t)1024 * 768 * 2;
    float* t_f32  = c_f32;  // overlay: c dead after last gates_lstm
    f16* h_hi[2] = {h_hi0, h_hi1};
    f16* h_lo[2] = {h_lo0, h_lo1};

    hipMemsetAsync(c_f32, 0, (size_t)1024 * 1024 * 4, stream);
    hipMemsetAsync(h_hi0, 0, (size_t)1024 * 1024 * 2, stream);
    hipMemsetAsync(h_lo0, 0, (size_t)1024 * 1024 * 2, stream);

    swz_w<<<56 * 32, 256, 0, stream>>>(W_ih, W_hh, Wswz);

    for (int t = 0; t < 16; t++) {
        int rb = t & 1, wb = 1 - rb;
        att_glimpse<<<1024, 256, 0, stream>>>(
            h_hi[rb], h_lo[rb], W_att, b_att, x, r_hi, r_lo);
        gates_lstm<<<512, 256, 0, stream>>>(
            r_hi, r_lo, h_hi[rb], h_lo[rb], Wswz, b_ih, b_hh,
            c_f32, h_hi[wb], h_lo[wb]);
    }
    fc0_gemm<<<dim3(16, 16), 256, 0, stream>>>(
        h_hi[0], h_lo[0], W_fc0, b_fc0, t_f32);
    fc_out<<<1024, 64, 0, stream>>>(t_f32, W_fc, b_fc, out);
}

// Round 16
// 1321.315 us; speedup vs baseline: 1.2585x; 1.0605x over previous
//
#include <hip/hip_runtime.h>

typedef unsigned short u16;
typedef unsigned int u32;
typedef _Float16 f16;
typedef _Float16 half8 __attribute__((ext_vector_type(8)));
typedef _Float16 half4 __attribute__((ext_vector_type(4)));
typedef float f32x4 __attribute__((ext_vector_type(4)));

#define SPLIT_SC 2048.0f
#define SPLIT_INV (1.0f / 2048.0f)

__device__ __forceinline__ float sigf(float x) { return 1.0f / (1.0f + expf(-x)); }

// ---------------------------------------------------------------------------
// Fused attention-params + filterbank + glimpse, v7.
// Round-15 verified v6 structure (grid 1024, in-block channel loop, shared
// phase A + filterbank) but stage 1 reads the image DIRECTLY from global
// (coalesced float4, L2-resident) instead of staging through LDS: deletes
// the 48 KB/blk copy traffic (96 of ~140 b128 LDS ops/wave) and one
// barrier per channel.  Values and accumulation order unchanged.
// ---------------------------------------------------------------------------
__global__ __launch_bounds__(256) void att_glimpse(
    const f16* __restrict__ h_hi, const f16* __restrict__ h_lo,
    const float* __restrict__ Watt, const float* __restrict__ batt,
    const float* __restrict__ x,
    f16* __restrict__ r_hi, f16* __restrict__ r_lo)
{
    __shared__ float sFx[16 * 68];       // [xo][a], stride 68
    __shared__ float sFyT[64 * 20];      // [y][n],  stride 20
    __shared__ float stmp[16 * 68];      // [n][a],  stride 68
    __shared__ float sred[4 * 5];
    __shared__ float spar[8];

    const int b = blockIdx.x, tid = threadIdx.x;
    const int lane = tid & 63, wave = tid >> 6;

    // phase A: p = h[b] @ Watt^T + batt (5 dots of length 1024), fp32
    float p[5] = {0.f, 0.f, 0.f, 0.f, 0.f};
    {
        const f16* hh = h_hi + (size_t)b * 1024;
        const f16* hl = h_lo + (size_t)b * 1024;
        for (int k = tid; k < 1024; k += 256) {
            float hv = (float)hh[k] + (float)hl[k] * SPLIT_INV;
#pragma unroll
            for (int j = 0; j < 5; j++) p[j] += hv * Watt[j * 1024 + k];
        }
#pragma unroll
        for (int j = 0; j < 5; j++) {
#pragma unroll
            for (int o = 32; o > 0; o >>= 1) p[j] += __shfl_xor(p[j], o);
        }
        if (lane == 0) {
#pragma unroll
            for (int j = 0; j < 5; j++) sred[wave * 5 + j] = p[j];
        }
    }
    __syncthreads();
    if (tid == 0) {
        float q[5];
#pragma unroll
        for (int j = 0; j < 5; j++)
            q[j] = sred[j] + sred[5 + j] + sred[10 + j] + sred[15 + j] + batt[j];
        float q2 = fminf(fmaxf(q[2], -60.f), 60.f);
        float q3 = fminf(fmaxf(q[3], -60.f), 60.f);
        float q4 = fminf(fmaxf(q[4], -60.f), 60.f);
        spar[0] = 32.5f * (q[0] + 1.0f);          // gx
        spar[1] = 32.5f * (q[1] + 1.0f);          // gy
        spar[2] = 0.5f * expf(-q2);               // 1/(2*sigma2)
        spar[3] = 4.2f * expf(q3);                // delta
        spar[4] = expf(q4);                       // gamma
    }
    __syncthreads();
    const float gx = spar[0], gy = spar[1], inv2s2 = spar[2], dl = spar[3],
                gamma = spar[4];

    // phase B: filterbank (once).  wave w: n = w, w+4, w+8, w+12; lane = px
    {
        const float af = (float)lane;
#pragma unroll
        for (int i = 0; i < 4; i++) {
            int n = wave + i * 4;
            float nn = (float)n - 8.5f;
            float mux = gx + nn * dl;
            float ex = af - mux;
            float vx = expf(-ex * ex * inv2s2);
            float sx = vx;
#pragma unroll
            for (int o = 32; o > 0; o >>= 1) sx += __shfl_xor(sx, o);
            sFx[n * 68 + lane] = vx / (sx + 1e-8f);

            float muy = gy + nn * dl;
            float ey = af - muy;
            float vy = expf(-ey * ey * inv2s2);
            float sy = vy;
#pragma unroll
            for (int o = 32; o > 0; o >>= 1) sy += __shfl_xor(sy, o);
            sFyT[lane * 20 + n] = vy / (sy + 1e-8f);   // transposed [y][n]
        }
    }

    // channel loop: stage1 (img direct from global) -> stage2
    for (int c = 0; c < 3; c++) {
        __syncthreads();   // sFx/sFyT ready (c=0); stmp reads done (c>0)

        // stage 1 (all 4 waves): tmp[n][a] = sum_y Fy[n][y] * img[y][a]
        {
            const int n4 = wave, ysub = lane >> 4, a4 = lane & 15;
            const float* xg = x + (size_t)b * 12288 + c * 4096;
            f32x4 acc[4];
#pragma unroll
            for (int j = 0; j < 4; j++) acc[j] = (f32x4)(0.f);
#pragma unroll
            for (int yy = 0; yy < 16; yy++) {
                int y = ysub * 16 + yy;
                float4 im = *(const float4*)(xg + y * 64 + a4 * 4);   // global
                float4 fy = *(const float4*)(sFyT + y * 20 + n4 * 4); // LDS
                f32x4 iv = {im.x, im.y, im.z, im.w};
                acc[0] += fy.x * iv;
                acc[1] += fy.y * iv;
                acc[2] += fy.z * iv;
                acc[3] += fy.w * iv;
            }
#pragma unroll
            for (int j = 0; j < 4; j++) {
#pragma unroll
                for (int o = 16; o <= 32; o <<= 1) {
                    acc[j].x += __shfl_xor(acc[j].x, o);
                    acc[j].y += __shfl_xor(acc[j].y, o);
                    acc[j].z += __shfl_xor(acc[j].z, o);
                    acc[j].w += __shfl_xor(acc[j].w, o);
                }
            }
            if (ysub == 0) {
#pragma unroll
                for (int j = 0; j < 4; j++)
                    *(f32x4*)(stmp + (n4 * 4 + j) * 68 + a4 * 4) = acc[j];
            }
        }
        __syncthreads();

        // stage 2: r[n][xo] = gamma * sum_a tmp[n][a] * Fx[xo][a]
        {
            const int n = tid >> 4, xo = tid & 15;
            const float* tp = stmp + n * 68;
            const float* fx = sFx + xo * 68;
            float s = 0.f;
            for (int a = 0; a < 64; a += 4) {
                float4 t4 = *(const float4*)(tp + a);
                float4 x4 = *(const float4*)(fx + a);
                s += t4.x * x4.x + t4.y * x4.y + t4.z * x4.z + t4.w * x4.w;
            }
            float v = s * gamma;
            f16 hi = (f16)v;
            size_t idx = (size_t)b * 768 + c * 256 + tid;
            r_hi[idx] = hi;
            r_lo[idx] = (f16)((v - (float)hi) * SPLIT_SC);
        }
    }
}

// ---------------------------------------------------------------------------
// W pre-swizzle v2 (round-12 verified): gate = (c&1)*2 + (l15>>3),
// u_local = (c>>1)*8 + (l15&7) -> lane pairs (l15, l15^8) hold all 4 gates.
// ---------------------------------------------------------------------------
__global__ __launch_bounds__(256) void swz_w(
    const float* __restrict__ W1, const float* __restrict__ W2,
    f16* __restrict__ out)
{
    const int kc = blockIdx.x >> 5, bn = blockIdx.x & 31;
    for (int t = threadIdx.x; t < 512; t += 256) {
        int c = t >> 6, lane = t & 63, l15 = lane & 15, lq = lane >> 4;
        int gate = ((c & 1) << 1) + (l15 >> 3);
        int ul   = ((c >> 1) << 3) + (l15 & 7);
        int wrow = gate * 1024 + bn * 32 + ul;
        const float* src;
        if (kc < 24) src = W1 + (size_t)wrow * 768 + kc * 32 + lq * 8;
        else         src = W2 + (size_t)wrow * 1024 + (kc - 24) * 32 + lq * 8;
        float4 g0 = *(const float4*)src;
        float4 g1 = *(const float4*)(src + 4);
        float gv[8] = {g0.x, g0.y, g0.z, g0.w, g1.x, g1.y, g1.z, g1.w};
        half8 hv, lv;
#pragma unroll
        for (int j = 0; j < 8; j++) {
            f16 h = (f16)gv[j];
            hv[j] = h;
            lv[j] = (f16)((gv[j] - (float)h) * SPLIT_SC);
        }
        size_t base = ((size_t)(kc * 32 + bn) * 16 + c * 2) * 512 + (size_t)lane * 8;
        *(half8*)(out + base) = hv;
        *(half8*)(out + base + 512) = lv;
    }
}

// ---------------------------------------------------------------------------
// Fused gates GEMM + LSTM pointwise, v10.
// v7 (round-12/15 verified 56.4us) with BK=64: 28 K-iterations instead of
// 56 -> half the barrier+vmcnt-drain events (the never-varied axis).
// Per iter: 2 kc-chunks, 48 MFMA/wave.  K-chunk order preserved ->
// bit-identical accumulation.  LDS 36.9 KB, still 2 blocks/CU.
// ---------------------------------------------------------------------------
#define LDH2 72   // A LDS row stride in f16 elems (144 B; rows r,r+8 2-way = free)

__global__ __launch_bounds__(256, 2) void gates_lstm(
    const f16* __restrict__ A1h, const f16* __restrict__ A1l,  // r [1024][768]
    const f16* __restrict__ A2h, const f16* __restrict__ A2l,  // h [1024][1024]
    const f16* __restrict__ Wswz,                               // swizzled W
    const float* __restrict__ b1, const float* __restrict__ b2,
    float* __restrict__ cst,
    f16* __restrict__ Hh, f16* __restrict__ Hl)
{
    __shared__ f16 sA[2][2][64 * LDH2];  // [buf][plane] 36.9 KB total
    const int tid = threadIdx.x;
    const int kb = blockIdx.x;           // 0..511
    const int xcd = kb & 7, jb = kb >> 3;
    const int bn = xcd * 4 + (jb & 3);   // 0..31
    const int bm = jb >> 2;              // 0..15
    const int wave = tid >> 6, lane = tid & 63;
    const int cbase = wave * 2;          // disjoint ctile pair per wave
    const int l15 = lane & 15, lq = lane >> 4;
    const int arow = tid >> 3, acol = (tid & 7) * 8;  // 2 row-chunks/thread/plane

    f32x4 ah[4][2], al[4][2];
#pragma unroll
    for (int i = 0; i < 4; i++)
#pragma unroll
        for (int j = 0; j < 2; j++) { ah[i][j] = (f32x4)(0.f); al[i][j] = (f32x4)(0.f); }

    // prologue: stage A(i=0: k 0..63 of r) into buf0, load B fragments
    {
        size_t a0 = (size_t)(bm * 64 + arow) * 768 + acol;
        size_t a1 = (size_t)(bm * 64 + arow + 32) * 768 + acol;
        *(uint4*)&sA[0][0][arow * LDH2 + acol]        = *(const uint4*)(A1h + a0);
        *(uint4*)&sA[0][0][(arow + 32) * LDH2 + acol] = *(const uint4*)(A1h + a1);
        *(uint4*)&sA[0][1][arow * LDH2 + acol]        = *(const uint4*)(A1l + a0);
        *(uint4*)&sA[0][1][(arow + 32) * LDH2 + acol] = *(const uint4*)(A1l + a1);
    }
    half8 Bc[8];
#pragma unroll
    for (int sub = 0; sub < 2; sub++) {
        const f16* wb = Wswz + (size_t)(sub * 32 + bn) * 16 * 512 + (size_t)lane * 8;
#pragma unroll
        for (int nt = 0; nt < 2; nt++) {
            Bc[sub * 4 + nt * 2]     = *(const half8*)(wb + (cbase + nt) * 1024);
            Bc[sub * 4 + nt * 2 + 1] = *(const half8*)(wb + (cbase + nt) * 1024 + 512);
        }
    }

#pragma unroll 2
    for (int i = 0; i < 28; ++i) {
        const int cur = i & 1;
        __syncthreads();                 // buf[cur] ready, prev reads drained
        const int kn = (i + 1 < 28) ? i + 1 : 27;
        // ---- prefetch A(kn) to regs (64 rows x 64 k, hi+lo) ----
        const f16 *pah, *pal; int astr, ako;
        if (kn < 12) { pah = A1h; pal = A1l; astr = 768;  ako = kn * 64; }
        else         { pah = A2h; pal = A2l; astr = 1024; ako = (kn - 12) * 64; }
        size_t a0 = (size_t)(bm * 64 + arow) * astr + ako + acol;
        size_t a1 = (size_t)(bm * 64 + arow + 32) * astr + ako + acol;
        uint4 vh0 = *(const uint4*)(pah + a0);
        uint4 vh1 = *(const uint4*)(pah + a1);
        uint4 vl0 = *(const uint4*)(pal + a0);
        uint4 vl1 = *(const uint4*)(pal + a1);
        // ---- prefetch B(kn) fragments (2 kc-chunks) ----
        half8 Bn[8];
#pragma unroll
        for (int sub = 0; sub < 2; sub++) {
            const f16* wb = Wswz + (size_t)((kn * 2 + sub) * 32 + bn) * 16 * 512
                          + (size_t)lane * 8;
#pragma unroll
            for (int nt = 0; nt < 2; nt++) {
                Bn[sub * 4 + nt * 2]     = *(const half8*)(wb + (cbase + nt) * 1024);
                Bn[sub * 4 + nt * 2 + 1] = *(const half8*)(wb + (cbase + nt) * 1024 + 512);
            }
        }
        // ---- compute on buf[cur]: 2 kc-chunks x 4 m-tiles x 2 c-tiles ----
#pragma unroll
        for (int sub = 0; sub < 2; sub++) {
            half8 afh[4], afl[4];
#pragma unroll
            for (int mt = 0; mt < 4; mt++) {
                int ro = (mt * 16 + l15) * LDH2 + sub * 32 + lq * 8;
                afh[mt] = *(const half8*)&sA[cur][0][ro];
                afl[mt] = *(const half8*)&sA[cur][1][ro];
            }
#pragma unroll
            for (int mt = 0; mt < 4; mt++)
#pragma unroll
                for (int nt = 0; nt < 2; nt++) {
                    ah[mt][nt] = __builtin_amdgcn_mfma_f32_16x16x32_f16(
                        afh[mt], Bc[sub * 4 + nt * 2], ah[mt][nt], 0, 0, 0);
                    al[mt][nt] = __builtin_amdgcn_mfma_f32_16x16x32_f16(
                        afh[mt], Bc[sub * 4 + nt * 2 + 1], al[mt][nt], 0, 0, 0);
                    al[mt][nt] = __builtin_amdgcn_mfma_f32_16x16x32_f16(
                        afl[mt], Bc[sub * 4 + nt * 2], al[mt][nt], 0, 0, 0);
                }
        }
        // ---- write prefetched A into the other buffer, rotate B ----
        const int nxt = cur ^ 1;
        *(uint4*)&sA[nxt][0][arow * LDH2 + acol]        = vh0;
        *(uint4*)&sA[nxt][0][(arow + 32) * LDH2 + acol] = vh1;
        *(uint4*)&sA[nxt][1][arow * LDH2 + acol]        = vl0;
        *(uint4*)&sA[nxt][1][(arow + 32) * LDH2 + acol] = vl1;
#pragma unroll
        for (int q = 0; q < 8; q++) Bc[q] = Bn[q];
    }

    // epilogue (v7-verified): lane holds gates {g0, g0+2}, g0 = l15>>3, at
    // u = bn*32 + wave*8 + (l15&7); partner lane l15^8 holds the other pair.
    const int g0 = l15 >> 3;
    const int u = bn * 32 + wave * 8 + (l15 & 7);
    const float bv0 = b1[g0 * 1024 + u] + b2[g0 * 1024 + u];
    const float bv1 = b1[(g0 + 2) * 1024 + u] + b2[(g0 + 2) * 1024 + u];
#pragma unroll
    for (int mt = 0; mt < 4; mt++) {
#pragma unroll
        for (int rg = 0; rg < 4; rg++) {
            int row = bm * 64 + mt * 16 + lq * 4 + rg;
            size_t idx = (size_t)row * 1024 + u;
            float mine0 = ah[mt][0][rg] + al[mt][0][rg] * SPLIT_INV + bv0;
            float mine1 = ah[mt][1][rg] + al[mt][1][rg] * SPLIT_INV + bv1;
            float oth0 = __shfl_xor(mine0, 8);
            float oth1 = __shfl_xor(mine1, 8);
            float gi = (g0 == 0) ? mine0 : oth0;
            float gg = (g0 == 0) ? mine1 : oth1;
            float gf = (g0 == 0) ? oth0 : mine0;
            float go = (g0 == 0) ? oth1 : mine1;
            if (g0 == 0) {
                float cn = sigf(gf) * cst[idx] + sigf(gi) * tanhf(gg);
                float hn = sigf(go) * tanhf(cn);
                cst[idx] = cn;
                f16 hh = (f16)hn;
                Hh[idx] = hh;
                Hl[idx] = (f16)((hn - (float)hh) * SPLIT_SC);
            }
        }
    }
}

// ---------------------------------------------------------------------------
// fc0 v3 (round-10/12 verified): 64x64 tiles, grid (16,16).
// ---------------------------------------------------------------------------
#define LDH 40

__global__ __launch_bounds__(256) void fc0_gemm(
    const f16* __restrict__ Ah, const f16* __restrict__ Al,
    const float* __restrict__ W, const float* __restrict__ bias,
    float* __restrict__ out)
{
    __shared__ f16 sAh[64 * LDH], sAl[64 * LDH];
    __shared__ f16 sBh[64 * LDH], sBl[64 * LDH];
    const int tid = threadIdx.x;
    const int bm = blockIdx.x, bn = blockIdx.y;
    const int wave = tid >> 6, lane = tid & 63;
    const int wm = (wave >> 1) * 32, wn = (wave & 1) * 32;
    const int l15 = lane & 15, lq = lane >> 4;

    f32x4 ach[2][2], acx[2][2];
#pragma unroll
    for (int i = 0; i < 2; i++)
#pragma unroll
        for (int j = 0; j < 2; j++) { ach[i][j] = (f32x4)(0.f); acx[i][j] = (f32x4)(0.f); }

    for (int kc = 0; kc < 1024; kc += 32) {
        {
            int e = tid * 8;
            int row = e >> 5, col = e & 31;
            size_t off = (size_t)(bm * 64 + row) * 1024 + kc + col;
            *(uint4*)&sAh[row * LDH + col] = *(const uint4*)(Ah + off);
            *(uint4*)&sAl[row * LDH + col] = *(const uint4*)(Al + off);
        }
#pragma unroll
        for (int l = 0; l < 2; l++) {
            int e = (l * 256 + tid) * 4;
            int crow = e >> 5, col = e & 31;
            float4 g = *(const float4*)(W + (size_t)(bn * 64 + crow) * 1024 + kc + col);
            f16 h0 = (f16)g.x, h1 = (f16)g.y, h2 = (f16)g.z, h3 = (f16)g.w;
            half4 hv = {h0, h1, h2, h3};
            half4 lv = {(f16)((g.x - (float)h0) * SPLIT_SC),
                        (f16)((g.y - (float)h1) * SPLIT_SC),
                        (f16)((g.z - (float)h2) * SPLIT_SC),
                        (f16)((g.w - (float)h3) * SPLIT_SC)};
            *(half4*)&sBh[crow * LDH + col] = hv;
            *(half4*)&sBl[crow * LDH + col] = lv;
        }
        __syncthreads();
        half8 afh[2], afl[2], bfh[2], bfl[2];
#pragma unroll
        for (int mt = 0; mt < 2; mt++) {
            int ro = (wm + mt * 16 + l15) * LDH + lq * 8;
            afh[mt] = *(const half8*)&sAh[ro];
            afl[mt] = *(const half8*)&sAl[ro];
        }
#pragma unroll
        for (int nt = 0; nt < 2; nt++) {
            int ro = (wn + nt * 16 + l15) * LDH + lq * 8;
            bfh[nt] = *(const half8*)&sBh[ro];
            bfl[nt] = *(const half8*)&sBl[ro];
        }
#pragma unroll
        for (int mt = 0; mt < 2; mt++)
#pragma unroll
            for (int nt = 0; nt < 2; nt++) {
                ach[mt][nt] = __builtin_amdgcn_mfma_f32_16x16x32_f16(
                    afh[mt], bfh[nt], ach[mt][nt], 0, 0, 0);
                acx[mt][nt] = __builtin_amdgcn_mfma_f32_16x16x32_f16(
                    afh[mt], bfl[nt], acx[mt][nt], 0, 0, 0);
                acx[mt][nt] = __builtin_amdgcn_mfma_f32_16x16x32_f16(
                    afl[mt], bfh[nt], acx[mt][nt], 0, 0, 0);
            }
        __syncthreads();
    }

#pragma unroll
    for (int mt = 0; mt < 2; mt++) {
#pragma unroll
        for (int nt = 0; nt < 2; nt++) {
            int col = bn * 64 + wn + nt * 16 + l15;
            float bv = bias[col];
#pragma unroll
            for (int rg = 0; rg < 4; rg++) {
                int row = bm * 64 + wm + mt * 16 + lq * 4 + rg;
                float v = ach[mt][nt][rg] + acx[mt][nt][rg] * SPLIT_INV + bv;
                out[(size_t)row * 1024 + col] = fmaxf(v, 0.f);
            }
        }
    }
}

// ---------------------------------------------------------------------------
// final tiny fc: out[b][j] = t[b] . W_fc[j] + b_fc[j], j < 10, fp32 out
// ---------------------------------------------------------------------------
__global__ __launch_bounds__(64) void fc_out(
    const float* __restrict__ tb, const float* __restrict__ Wfc,
    const float* __restrict__ bfc, float* __restrict__ out)
{
    int b = blockIdx.x, lane = threadIdx.x;
    const float* tv = tb + (size_t)b * 1024;
    float p[10];
#pragma unroll
    for (int j = 0; j < 10; j++) p[j] = 0.f;
    for (int k = lane; k < 1024; k += 64) {
        float t = tv[k];
#pragma unroll
        for (int j = 0; j < 10; j++) p[j] += t * Wfc[j * 1024 + k];
    }
#pragma unroll
    for (int j = 0; j < 10; j++) {
#pragma unroll
        for (int o = 32; o > 0; o >>= 1) p[j] += __shfl_xor(p[j], o);
    }
    if (lane == 0) {
#pragma unroll
        for (int j = 0; j < 10; j++) out[b * 10 + j] = p[j] + bfc[j];
    }
}

extern "C" void kernel_launch(void* const* d_in, const int* in_sizes, int n_in,
                              void* d_out, int out_size, void* d_ws, size_t ws_size,
                              hipStream_t stream)
{
    const float* x     = (const float*)d_in[0];
    const float* W_att = (const float*)d_in[1];
    const float* b_att = (const float*)d_in[2];
    const float* W_ih  = (const float*)d_in[3];
    const float* W_hh  = (const float*)d_in[4];
    const float* b_ih  = (const float*)d_in[5];
    const float* b_hh  = (const float*)d_in[6];
    const float* W_fc0 = (const float*)d_in[7];
    const float* b_fc0 = (const float*)d_in[8];
    const float* W_fc  = (const float*)d_in[9];
    const float* b_fc  = (const float*)d_in[10];
    float* out = (float*)d_out;

    // Workspace (~44.5 MB, verified): Wswz | c | h planes x4 | r x2
    char* ws = (char*)d_ws;
    f16*   Wswz   = (f16*)ws;    ws += (size_t)56 * 32 * 16 * 512 * 2;  // 29.36 MB
    float* c_f32  = (float*)ws;  ws += (size_t)1024 * 1024 * 4;         // 4 MB
    f16*   h_hi0  = (f16*)ws;    ws += (size_t)1024 * 1024 * 2;
    f16*   h_hi1  = (f16*)ws;    ws += (size_t)1024 * 1024 * 2;
    f16*   h_lo0  = (f16*)ws;    ws += (size_t)1024 * 1024 * 2;
    f16*   h_lo1  = (f16*)ws;    ws += (size_t)1024 * 1024 * 2;
    f16*   r_hi   = (f16*)ws;    ws += (size_t)1024 * 768 * 2;
    f16*   r_lo   = (f16*)ws;    ws += (size_t)1024 * 768 * 2;
    float* t_f32  = c_f32;  // overlay: c dead after last gates_lstm
    f16* h_hi[2] = {h_hi0, h_hi1};
    f16* h_lo[2] = {h_lo0, h_lo1};

    hipMemsetAsync(c_f32, 0, (size_t)1024 * 1024 * 4, stream);
    hipMemsetAsync(h_hi0, 0, (size_t)1024 * 1024 * 2, stream);
    hipMemsetAsync(h_lo0, 0, (size_t)1024 * 1024 * 2, stream);

    swz_w<<<56 * 32, 256, 0, stream>>>(W_ih, W_hh, Wswz);

    for (int t = 0; t < 16; t++) {
        int rb = t & 1, wb = 1 - rb;
        att_glimpse<<<1024, 256, 0, stream>>>(
            h_hi[rb], h_lo[rb], W_att, b_att, x, r_hi, r_lo);
        gates_lstm<<<512, 256, 0, stream>>>(
            r_hi, r_lo, h_hi[rb], h_lo[rb], Wswz, b_ih, b_hh,
            c_f32, h_hi[wb], h_lo[wb]);
    }
    fc0_gemm<<<dim3(16, 16), 256, 0, stream>>>(
        h_hi[0], h_lo[0], W_fc0, b_fc0, t_f32);
    fc_out<<<1024, 64, 0, stream>>>(t_f32, W_fc, b_fc, out);
}